// Round 14
// baseline (246.114 us; speedup 1.0000x reference)
//
#include <hip/hip_runtime.h>

#define DIM 128
#define CAP 512                    // rows staged as bf16 in LDS per graph
#define MAXT 24                    // 24 x 32 = 768 rows staged bf16 in regs (48 VGPR)
#define NTHREADS 1024              // 16 waves/block, 1 block/CU (LDS-bound)

typedef float fx4 __attribute__((ext_vector_type(4)));

#define STAGE_BYTES (CAP * 32 * 8)            // 131072
#define RED_BYTES   (16 * 32 * 16)            // 8192 (fx4[16][32]; aliased by wred)
#define SMEM_BYTES  (STAGE_BYTES + RED_BYTES + 2 * DIM * 4 + 16)

// round-to-nearest-even f32 -> bf16 bits
__device__ __forceinline__ unsigned bfr(float f) {
    unsigned u = __float_as_uint(f);
    return (u + 0x7fffu + ((u >> 16) & 1u)) >> 16;
}
__device__ __forceinline__ uint2 pack4(fx4 v) {
    return make_uint2(bfr(v.x) | (bfr(v.y) << 16), bfr(v.z) | (bfr(v.w) << 16));
}
__device__ __forceinline__ fx4 unpack4(uint2 u) {
    fx4 r;
    r.x = __uint_as_float(u.x << 16);
    r.y = __uint_as_float(u.x & 0xffff0000u);
    r.z = __uint_as_float(u.y << 16);
    r.w = __uint_as_float(u.y & 0xffff0000u);
    return r;
}

// first index i in [0,n) with seg[i] >= val  (seg sorted ascending)
__device__ __forceinline__ int lb_search(const int* __restrict__ seg, int n, int val) {
    int lo = 0, hi = n;
    while (lo < hi) {
        int mid = (lo + hi) >> 1;
        if (seg[mid] < val) lo = mid + 1; else hi = mid;
    }
    return lo;
}

// ---------------------------------------------------------------------------
// offsets kernel (tiny): offs[g] = first row with seg >= g.
// ---------------------------------------------------------------------------
__global__ void k_offsets(const int* __restrict__ seg, int* __restrict__ offs,
                          int n, int ngraphs) {
    const int i = blockIdx.x * blockDim.x + threadIdx.x;
    if (i >= n) return;
    const int a = seg[i];
    if (i == 0) {
        for (int g = 0; g <= a; ++g) offs[g] = 0;
    } else {
        const int p = seg[i - 1];
        for (int g = p + 1; g <= a; ++g) offs[g] = i;
    }
    if (i == n - 1) {
        for (int g = a + 1; g <= ngraphs; ++g) offs[g] = n;
    }
}

// ---------------------------------------------------------------------------
// One block per graph; blocks fully independent (R11 structure).
//   P1a: rows [rs, rs+CAP): f32 accumulate + bf16 stage to LDS (2-deep ILP).
//   P1b: rows [rs+CAP, rs+CAP+768): f32 accumulate + bf16 pack in REGISTERS
//        (tl[24] uint2, compile-time indices — 48 VGPR, same as R11's f32x12).
//   P1c: overflow rows (coverage 1280 = mean+9.8 sigma -> statistically
//        empty): accumulate only.
//   P2:  pool -> vn_new, block-local (pool never leaves LDS).
//   P3:  h_out = staged(LDS bf16 | regs bf16 | re-read) + vn_new; nt-stores.
// ---------------------------------------------------------------------------
__global__ __launch_bounds__(NTHREADS, 4) void k_fused(
        const float* __restrict__ h, const float* __restrict__ vn_h,
        const int* __restrict__ seg, const float* __restrict__ W,
        const float* __restrict__ bias, const int* __restrict__ offs,
        float* __restrict__ vn_out, float* __restrict__ h_out,
        int N, int G) {
    extern __shared__ char smem[];
    uint2* stage = (uint2*)smem;                          // [CAP*32]
    fx4*   red   = (fx4*)(smem + STAGE_BYTES);            // [16][32]
    float* wred  = (float*)(smem + STAGE_BYTES);          // [128*9] (alias)
    float* xs    = (float*)(smem + STAGE_BYTES + RED_BYTES);
    float* vns   = xs + DIM;
    int*   bnd   = (int*)(vns + DIM);

    const int g   = blockIdx.x;
    const int tid = threadIdx.x;
    const int tx  = tid & 31;          // float4 column
    const int ty  = tid >> 5;          // row slot (32 rows in flight)

    int rs, re;
    if (offs) {
        rs = offs[g];                  // uniform, L2-broadcast
        re = offs[g + 1];
    } else {
        if (tid < 2) bnd[tid] = lb_search(seg, N, g + tid);
        __syncthreads();
        rs = bnd[0];
        re = bnd[1];
    }
    const int n = re - rs;

    // ---- P1a: LDS-staged rows (2-deep unroll, R11-identical) ----
    fx4 a0 = {0.f,0.f,0.f,0.f}, a1 = {0.f,0.f,0.f,0.f};
    const int lim1 = min(rs + CAP, re);
    {
        int r = rs + ty;
        for (; r + 32 < lim1; r += 64) {
            const fx4 v0 = *(const fx4*)(h + (size_t)r        * DIM + tx * 4);
            const fx4 v1 = *(const fx4*)(h + (size_t)(r + 32) * DIM + tx * 4);
            a0 += v0; a1 += v1;
            stage[(r - rs)      * 32 + tx] = pack4(v0);
            stage[(r - rs + 32) * 32 + tx] = pack4(v1);
        }
        if (r < lim1) {
            const fx4 v = *(const fx4*)(h + (size_t)r * DIM + tx * 4);
            a0 += v;
            stage[(r - rs) * 32 + tx] = pack4(v);
        }
    }

    // ---- P1b: register-staged rows, bf16-packed (compile-time indices) ----
    uint2 tl[MAXT];
    const int tb = rs + CAP;
    #pragma unroll
    for (int j = 0; j < MAXT; ++j) {
        const int rr = tb + j * 32 + ty;
        fx4 v = {0.f, 0.f, 0.f, 0.f};
        if (rr < re) v = *(const fx4*)(h + (size_t)rr * DIM + tx * 4);
        tl[j] = pack4(v);
        a1 += v;
    }

    // ---- P1c: overflow rows (statistically empty at coverage 1280) ----
    for (int r = tb + MAXT * 32 + ty; r < re; r += 32)
        a0 += *(const fx4*)(h + (size_t)r * DIM + tx * 4);

    a0 += a1;
    fx4 t = a0;
    t.x += __shfl_xor(a0.x, 32);
    t.y += __shfl_xor(a0.y, 32);
    t.z += __shfl_xor(a0.z, 32);
    t.w += __shfl_xor(a0.w, 32);
    if ((tid & 32) == 0) red[(ty >> 1) * 32 + tx] = t;
    __syncthreads();

    // ---- pool + x = vn_h + pool (block-local, threads 0..31) ----
    if (tid < 32) {
        fx4 p2 = red[tx];
        #pragma unroll
        for (int w = 1; w < 16; ++w) p2 += red[w * 32 + tx];
        const float inv = 1.0f / (float)max(n, 1);
        const fx4 vnh = *(const fx4*)(vn_h + (size_t)g * DIM + tx * 4);
        *(fx4*)(xs + tx * 4) = vnh + p2 * inv;
    }
    __syncthreads();

    // ---- P2: vn_new(g) = vn_h + relu(x @ W + b), 8-way split-k ----
    {
        const int d    = tid & (DIM - 1);
        const int part = tid >> 7;             // 0..7
        const int k0   = part * (DIM / 8);
        float dp = 0.f;
        #pragma unroll
        for (int k = 0; k < DIM / 8; ++k)
            dp = fmaf(xs[k0 + k], W[(size_t)(k0 + k) * DIM + d], dp);
        wred[d * 9 + part] = dp;
    }
    __syncthreads();
    if (tid < DIM) {
        float dot = bias[tid];
        #pragma unroll
        for (int p = 0; p < 8; ++p) dot += wred[tid * 9 + p];
        const float vn = vn_h[(size_t)g * DIM + tid] + fmaxf(dot, 0.0f);
        vns[tid] = vn;
        vn_out[(size_t)g * DIM + tid] = vn;
    }
    __syncthreads();

    // ---- P3: h_out = h + vn_new[g] ----
    {
        const fx4 vnv = *(const fx4*)(vns + tx * 4);
        // LDS-staged rows
        int r = rs + ty;
        for (; r + 32 < lim1; r += 64) {
            const int l0 = r - rs;
            __builtin_nontemporal_store(
                unpack4(stage[l0 * 32 + tx]) + vnv,
                (fx4*)(h_out + (size_t)r * DIM + tx * 4));
            __builtin_nontemporal_store(
                unpack4(stage[(l0 + 32) * 32 + tx]) + vnv,
                (fx4*)(h_out + (size_t)(r + 32) * DIM + tx * 4));
        }
        if (r < lim1) {
            __builtin_nontemporal_store(
                unpack4(stage[(r - rs) * 32 + tx]) + vnv,
                (fx4*)(h_out + (size_t)r * DIM + tx * 4));
        }
        // register-staged rows (bf16)
        #pragma unroll
        for (int j = 0; j < MAXT; ++j) {
            const int rr = tb + j * 32 + ty;
            if (rr < re)
                __builtin_nontemporal_store(
                    unpack4(tl[j]) + vnv,
                    (fx4*)(h_out + (size_t)rr * DIM + tx * 4));
        }
        // overflow rows (statistically never): re-read
        for (int r2 = tb + MAXT * 32 + ty; r2 < re; r2 += 32) {
            const fx4 hv = *(const fx4*)(h + (size_t)r2 * DIM + tx * 4);
            __builtin_nontemporal_store(
                hv + vnv, (fx4*)(h_out + (size_t)r2 * DIM + tx * 4));
        }
    }
}

// ---------------------------------------------------------------------------
extern "C" void kernel_launch(void* const* d_in, const int* in_sizes, int n_in,
                              void* d_out, int out_size, void* d_ws, size_t ws_size,
                              hipStream_t stream) {
    const float* h    = (const float*)d_in[0];
    const float* vn_h = (const float*)d_in[1];
    const int*   seg  = (const int*)d_in[2];
    const float* W    = (const float*)d_in[3];
    const float* bias = (const float*)d_in[4];

    int N = in_sizes[0] / DIM;     // 1,000,000
    int G = in_sizes[1] / DIM;     // 1024

    float* vn_out = (float*)d_out;                     // [G*DIM]
    float* h_out  = vn_out + (size_t)G * DIM;          // [N*DIM]

    // offs[G+1] in d_ws if it fits (4.1 KB); else in-kernel binary search.
    int* offs = nullptr;
    if (ws_size >= (size_t)(G + 1) * sizeof(int)) {
        offs = (int*)d_ws;
        hipLaunchKernelGGL(k_offsets, dim3((N + 255) / 256), dim3(256), 0,
                           stream, seg, offs, N, G);
    }

    hipFuncSetAttribute((const void*)k_fused,
                        hipFuncAttributeMaxDynamicSharedMemorySize, SMEM_BYTES);

    hipLaunchKernelGGL(k_fused, dim3(G), dim3(NTHREADS), SMEM_BYTES, stream,
                       h, vn_h, seg, W, bias, offs, vn_out, h_out, N, G);
}

// Round 15
// 202.028 us; speedup vs baseline: 1.2182x; 1.2182x over previous
//
#include <hip/hip_runtime.h>

#define DIM 128
#define CAP 512                    // rows staged as bf16 in LDS per graph
#define MAXT 12                    // 12 x 32 = 384 rows staged f32 in regs
#define NTHREADS 1024              // 16 waves/block, 1 block/CU (LDS-bound)

typedef float fx4 __attribute__((ext_vector_type(4)));

#define STAGE_BYTES (CAP * 32 * 8)            // 131072
#define RED_BYTES   (16 * 32 * 16)            // 8192 (fx4[16][32]; aliased by wred)
#define SMEM_BYTES  (STAGE_BYTES + RED_BYTES + 2 * DIM * 4 + 16)

// round-to-nearest-even f32 -> bf16 bits
__device__ __forceinline__ unsigned bfr(float f) {
    unsigned u = __float_as_uint(f);
    return (u + 0x7fffu + ((u >> 16) & 1u)) >> 16;
}
__device__ __forceinline__ uint2 pack4(fx4 v) {
    return make_uint2(bfr(v.x) | (bfr(v.y) << 16), bfr(v.z) | (bfr(v.w) << 16));
}
__device__ __forceinline__ fx4 unpack4(uint2 u) {
    fx4 r;
    r.x = __uint_as_float(u.x << 16);
    r.y = __uint_as_float(u.x & 0xffff0000u);
    r.z = __uint_as_float(u.y << 16);
    r.w = __uint_as_float(u.y & 0xffff0000u);
    return r;
}

// first index i in [0,n) with seg[i] >= val  (seg sorted ascending)
__device__ __forceinline__ int lb_search(const int* __restrict__ seg, int n, int val) {
    int lo = 0, hi = n;
    while (lo < hi) {
        int mid = (lo + hi) >> 1;
        if (seg[mid] < val) lo = mid + 1; else hi = mid;
    }
    return lo;
}

// ---------------------------------------------------------------------------
// offsets kernel (tiny): offs[g] = first row with seg >= g.
// ---------------------------------------------------------------------------
__global__ void k_offsets(const int* __restrict__ seg, int* __restrict__ offs,
                          int n, int ngraphs) {
    const int i = blockIdx.x * blockDim.x + threadIdx.x;
    if (i >= n) return;
    const int a = seg[i];
    if (i == 0) {
        for (int g = 0; g <= a; ++g) offs[g] = 0;
    } else {
        const int p = seg[i - 1];
        for (int g = p + 1; g <= a; ++g) offs[g] = i;
    }
    if (i == n - 1) {
        for (int g = a + 1; g <= ngraphs; ++g) offs[g] = n;
    }
}

// ---------------------------------------------------------------------------
// One block per graph; blocks fully independent (no atomics, no coop launch).
//   P1a: rows [rs, rs+CAP): f32 accumulate + bf16 stage to LDS.
//   P1b: rows [rs+CAP, rs+CAP+384): f32 accumulate + KEEP IN REGISTERS
//        (tl[12], compile-time indices — no scratch).
//   P1c: rows beyond: accumulate only (re-read in P3; rare, ~80 rows/graph).
//   P2:  pool -> vn_new, block-local (pool never leaves LDS).
//   P3:  h_out = staged(LDS bf16 | regs f32 | re-read) + vn_new; nt-stores.
// (R11 configuration — measured 202.6 us. R12/R13/R14 perturbations all
//  regressed: streaming loops tolerate no extra register state or VALU.)
// ---------------------------------------------------------------------------
__global__ __launch_bounds__(NTHREADS, 4) void k_fused(
        const float* __restrict__ h, const float* __restrict__ vn_h,
        const int* __restrict__ seg, const float* __restrict__ W,
        const float* __restrict__ bias, const int* __restrict__ offs,
        float* __restrict__ vn_out, float* __restrict__ h_out,
        int N, int G) {
    extern __shared__ char smem[];
    uint2* stage = (uint2*)smem;                          // [CAP*32]
    fx4*   red   = (fx4*)(smem + STAGE_BYTES);            // [16][32]
    float* wred  = (float*)(smem + STAGE_BYTES);          // [128*9] (alias)
    float* xs    = (float*)(smem + STAGE_BYTES + RED_BYTES);
    float* vns   = xs + DIM;
    int*   bnd   = (int*)(vns + DIM);

    const int g   = blockIdx.x;
    const int tid = threadIdx.x;
    const int tx  = tid & 31;          // float4 column
    const int ty  = tid >> 5;          // row slot (32 rows in flight)

    if (offs) {
        if (tid < 2) bnd[tid] = offs[g + tid];
    } else {
        if (tid < 2) bnd[tid] = lb_search(seg, N, g + tid);
    }
    __syncthreads();
    const int rs = bnd[0];
    const int re = bnd[1];
    const int n  = re - rs;

    // ---- P1a: LDS-staged rows ----
    fx4 a0 = {0.f,0.f,0.f,0.f}, a1 = {0.f,0.f,0.f,0.f};
    const int lim1 = min(rs + CAP, re);
    {
        int r = rs + ty;
        for (; r + 32 < lim1; r += 64) {
            const fx4 v0 = *(const fx4*)(h + (size_t)r        * DIM + tx * 4);
            const fx4 v1 = *(const fx4*)(h + (size_t)(r + 32) * DIM + tx * 4);
            a0 += v0; a1 += v1;
            stage[(r - rs)      * 32 + tx] = pack4(v0);
            stage[(r - rs + 32) * 32 + tx] = pack4(v1);
        }
        if (r < lim1) {
            const fx4 v = *(const fx4*)(h + (size_t)r * DIM + tx * 4);
            a0 += v;
            stage[(r - rs) * 32 + tx] = pack4(v);
        }
    }

    // ---- P1b: register-staged rows (compile-time indices) ----
    fx4 tl[MAXT];
    const int tb = rs + CAP;
    #pragma unroll
    for (int j = 0; j < MAXT; ++j) {
        const int rr = tb + j * 32 + ty;
        fx4 v = {0.f, 0.f, 0.f, 0.f};
        if (rr < re) v = *(const fx4*)(h + (size_t)rr * DIM + tx * 4);
        tl[j] = v;
        a1 += v;
    }

    // ---- P1c: overflow rows (accumulate only; re-read in P3) ----
    for (int r = tb + MAXT * 32 + ty; r < re; r += 32)
        a0 += *(const fx4*)(h + (size_t)r * DIM + tx * 4);

    a0 += a1;
    fx4 t = a0;
    t.x += __shfl_xor(a0.x, 32);
    t.y += __shfl_xor(a0.y, 32);
    t.z += __shfl_xor(a0.z, 32);
    t.w += __shfl_xor(a0.w, 32);
    if ((tid & 32) == 0) red[(ty >> 1) * 32 + tx] = t;
    __syncthreads();

    // ---- pool + x = vn_h + pool (block-local, threads 0..31) ----
    if (tid < 32) {
        fx4 p2 = red[tx];
        #pragma unroll
        for (int w = 1; w < 16; ++w) p2 += red[w * 32 + tx];
        const float inv = 1.0f / (float)max(n, 1);
        const fx4 vnh = *(const fx4*)(vn_h + (size_t)g * DIM + tx * 4);
        *(fx4*)(xs + tx * 4) = vnh + p2 * inv;
    }
    __syncthreads();

    // ---- P2: vn_new(g) = vn_h + relu(x @ W + b), 8-way split-k ----
    {
        const int d    = tid & (DIM - 1);
        const int part = tid >> 7;             // 0..7
        const int k0   = part * (DIM / 8);
        float dp = 0.f;
        #pragma unroll
        for (int k = 0; k < DIM / 8; ++k)
            dp = fmaf(xs[k0 + k], W[(size_t)(k0 + k) * DIM + d], dp);
        wred[d * 9 + part] = dp;
    }
    __syncthreads();
    if (tid < DIM) {
        float dot = bias[tid];
        #pragma unroll
        for (int p = 0; p < 8; ++p) dot += wred[tid * 9 + p];
        const float vn = vn_h[(size_t)g * DIM + tid] + fmaxf(dot, 0.0f);
        vns[tid] = vn;
        vn_out[(size_t)g * DIM + tid] = vn;
    }
    __syncthreads();

    // ---- P3: h_out = h + vn_new[g] ----
    {
        const fx4 vnv = *(const fx4*)(vns + tx * 4);
        // LDS-staged rows
        int r = rs + ty;
        for (; r + 32 < lim1; r += 64) {
            const int l0 = r - rs;
            __builtin_nontemporal_store(
                unpack4(stage[l0 * 32 + tx]) + vnv,
                (fx4*)(h_out + (size_t)r * DIM + tx * 4));
            __builtin_nontemporal_store(
                unpack4(stage[(l0 + 32) * 32 + tx]) + vnv,
                (fx4*)(h_out + (size_t)(r + 32) * DIM + tx * 4));
        }
        if (r < lim1) {
            __builtin_nontemporal_store(
                unpack4(stage[(r - rs) * 32 + tx]) + vnv,
                (fx4*)(h_out + (size_t)r * DIM + tx * 4));
        }
        // register-staged rows (f32 exact)
        #pragma unroll
        for (int j = 0; j < MAXT; ++j) {
            const int rr = tb + j * 32 + ty;
            if (rr < re)
                __builtin_nontemporal_store(
                    tl[j] + vnv, (fx4*)(h_out + (size_t)rr * DIM + tx * 4));
        }
        // overflow rows: re-read (L3-hot — read moments ago in P1c)
        for (int r2 = tb + MAXT * 32 + ty; r2 < re; r2 += 32) {
            const fx4 hv = *(const fx4*)(h + (size_t)r2 * DIM + tx * 4);
            __builtin_nontemporal_store(
                hv + vnv, (fx4*)(h_out + (size_t)r2 * DIM + tx * 4));
        }
    }
}

// ---------------------------------------------------------------------------
extern "C" void kernel_launch(void* const* d_in, const int* in_sizes, int n_in,
                              void* d_out, int out_size, void* d_ws, size_t ws_size,
                              hipStream_t stream) {
    const float* h    = (const float*)d_in[0];
    const float* vn_h = (const float*)d_in[1];
    const int*   seg  = (const int*)d_in[2];
    const float* W    = (const float*)d_in[3];
    const float* bias = (const float*)d_in[4];

    int N = in_sizes[0] / DIM;     // 1,000,000
    int G = in_sizes[1] / DIM;     // 1024

    float* vn_out = (float*)d_out;                     // [G*DIM]
    float* h_out  = vn_out + (size_t)G * DIM;          // [N*DIM]

    // offs[G+1] in d_ws if it fits (4.1 KB); else in-kernel binary search.
    int* offs = nullptr;
    if (ws_size >= (size_t)(G + 1) * sizeof(int)) {
        offs = (int*)d_ws;
        hipLaunchKernelGGL(k_offsets, dim3((N + 255) / 256), dim3(256), 0,
                           stream, seg, offs, N, G);
    }

    hipFuncSetAttribute((const void*)k_fused,
                        hipFuncAttributeMaxDynamicSharedMemorySize, SMEM_BYTES);

    hipLaunchKernelGGL(k_fused, dim3(G), dim3(NTHREADS), SMEM_BYTES, stream,
                       h, vn_h, seg, W, bias, offs, vn_out, h_out, N, G);
}